// Round 1
// baseline (380.660 us; speedup 1.0000x reference)
//
#include <hip/hip_runtime.h>
#include <cmath>

// Problem constants: B=1, H=64, W=128, C=256, 8 heads x 32 dim, 7x7 window.
#define HH 64
#define WW 128
#define CC 256
#define NHEAD 8
#define HDIM 32
#define NPIX (HH*WW)       // 8192
#define QKV_N (3*CC)       // 768

// ---------------------------------------------------------------------------
// Tiled fp32 GEMM with bias: C[M][N] = A[M][K] * B[K][N] + bias[N]
// BM=128, BN=64, BK=16, 256 threads, 8x4 micro-tile per thread.
// ---------------------------------------------------------------------------
__global__ __launch_bounds__(256)
void gemm_bias(const float* __restrict__ A, const float* __restrict__ B,
               const float* __restrict__ bias, float* __restrict__ C,
               int M, int N, int K)
{
    constexpr int BM = 128, BN = 64, BK = 16, TM = 8, TN = 4;
    __shared__ float As[BK][BM + 4];   // row stride 132 floats = 528B (16B aligned)
    __shared__ float Bs[BK][BN + 4];   // row stride 68 floats  = 272B (16B aligned)

    const int tid = threadIdx.x;
    const int tx  = tid & 15;          // n-direction, 16 groups of TN=4 -> 64
    const int ty  = tid >> 4;          // m-direction, 16 groups of TM=8 -> 128
    const int bm  = blockIdx.x * BM;
    const int bn  = blockIdx.y * BN;

    // staging assignments
    const int ar  = tid >> 1;          // 0..127 (A row within tile)
    const int ak  = (tid & 1) * 8;     // 0 or 8 (k offset, 8 floats)
    const int bkr = tid >> 4;          // 0..15  (B row within k-tile)
    const int bnc = (tid & 15) * 4;    // 0..60  (B col, float4)

    float acc[TM][TN];
#pragma unroll
    for (int i = 0; i < TM; ++i)
#pragma unroll
        for (int j = 0; j < TN; ++j) acc[i][j] = 0.f;

    for (int k0 = 0; k0 < K; k0 += BK) {
        float4 a0 = *(const float4*)(A + (size_t)(bm + ar) * K + k0 + ak);
        float4 a1 = *(const float4*)(A + (size_t)(bm + ar) * K + k0 + ak + 4);
        float4 b0 = *(const float4*)(B + (size_t)(k0 + bkr) * N + bn + bnc);

        __syncthreads();   // previous iteration's reads complete before overwrite
        As[ak + 0][ar] = a0.x; As[ak + 1][ar] = a0.y;
        As[ak + 2][ar] = a0.z; As[ak + 3][ar] = a0.w;
        As[ak + 4][ar] = a1.x; As[ak + 5][ar] = a1.y;
        As[ak + 6][ar] = a1.z; As[ak + 7][ar] = a1.w;
        *(float4*)&Bs[bkr][bnc] = b0;
        __syncthreads();

#pragma unroll
        for (int kk = 0; kk < BK; ++kk) {
            float4 av0 = *(const float4*)&As[kk][ty * TM];
            float4 av1 = *(const float4*)&As[kk][ty * TM + 4];
            float4 bv  = *(const float4*)&Bs[kk][tx * TN];
            float am[TM] = {av0.x, av0.y, av0.z, av0.w, av1.x, av1.y, av1.z, av1.w};
            float bb[TN] = {bv.x, bv.y, bv.z, bv.w};
#pragma unroll
            for (int i = 0; i < TM; ++i)
#pragma unroll
                for (int j = 0; j < TN; ++j)
                    acc[i][j] = fmaf(am[i], bb[j], acc[i][j]);
        }
    }

    float4 bvec = *(const float4*)(bias + bn + tx * TN);
#pragma unroll
    for (int i = 0; i < TM; ++i) {
        float4 o;
        o.x = acc[i][0] + bvec.x;
        o.y = acc[i][1] + bvec.y;
        o.z = acc[i][2] + bvec.z;
        o.w = acc[i][3] + bvec.w;
        *(float4*)(C + (size_t)(bm + ty * TM + i) * N + bn + tx * TN) = o;
    }
}

// ---------------------------------------------------------------------------
// Neighborhood attention. One block per (16x16 pixel tile, head), one thread
// per pixel. K then V staged (two-phase) in one 62KB LDS buffer with an XOR
// swizzle on the 16B granule (row stride is exactly 128B otherwise -> full
// bank pile-up).
// ---------------------------------------------------------------------------
#define UROWS 22   // 16 + 6 union rows/cols

__global__ __launch_bounds__(256)
void na_attn(const float* __restrict__ qkv, float* __restrict__ attn_out)
{
    __shared__ float kv_lds[UROWS * UROWS * HDIM];   // 61952 B

    const int head = blockIdx.z;
    const int h0 = blockIdx.y * 16;
    const int w0 = blockIdx.x * 16;
    const int hs = h0 - 3, ws = w0 - 3;   // union origin (may be negative)
    const int tid = threadIdx.x;

    // ---- stage K (qkv offset +256) ----
    for (int idx = tid; idx < UROWS * UROWS * 8; idx += 256) {
        int row = idx >> 3, seg = idx & 7;
        int r = row / UROWS, c = row - r * UROWS;
        int hh = hs + r, ww = ws + c;
        if (hh >= 0 && hh < HH && ww >= 0 && ww < WW) {
            float4 v = *(const float4*)(qkv + ((size_t)(hh * WW + ww)) * QKV_N
                                        + CC + head * HDIM + seg * 4);
            *(float4*)&kv_lds[row * HDIM + ((seg ^ (row & 7)) << 2)] = v;
        }
    }

    const int py = tid >> 4, px = tid & 15;
    const int gy = h0 + py, gx = w0 + px;
    const int ihs = min(max(gy - 3, 0), HH - 7);
    const int iws = min(max(gx - 3, 0), WW - 7);
    const int rbase = (ihs - hs) * UROWS + (iws - ws);
    const float scale = 0.17677669529663687f;   // 32^-0.5

    float q[HDIM];
    {
        const float* qp = qkv + ((size_t)(gy * WW + gx)) * QKV_N + head * HDIM;
#pragma unroll
        for (int s = 0; s < 8; ++s) {
            float4 v = *(const float4*)(qp + s * 4);
            q[4*s+0] = v.x * scale; q[4*s+1] = v.y * scale;
            q[4*s+2] = v.z * scale; q[4*s+3] = v.w * scale;
        }
    }
    __syncthreads();

    // ---- pass 1: logits ----
    float logits[49];
    float mx = -1e30f;
#pragma unroll
    for (int p = 0; p < 7; ++p) {
#pragma unroll
        for (int qq = 0; qq < 7; ++qq) {
            const int row = rbase + p * UROWS + qq;
            const float* kr = &kv_lds[row * HDIM];
            const int sw = (row & 7) << 2;
            float s = 0.f;
#pragma unroll
            for (int d4 = 0; d4 < 8; ++d4) {
                float4 k4 = *(const float4*)(kr + ((d4 << 2) ^ sw));
                s = fmaf(q[4*d4+0], k4.x, s);
                s = fmaf(q[4*d4+1], k4.y, s);
                s = fmaf(q[4*d4+2], k4.z, s);
                s = fmaf(q[4*d4+3], k4.w, s);
            }
            logits[p * 7 + qq] = s;
            mx = fmaxf(mx, s);
        }
    }
    __syncthreads();   // everyone done reading K

    // ---- stage V (qkv offset +512) ----
    for (int idx = tid; idx < UROWS * UROWS * 8; idx += 256) {
        int row = idx >> 3, seg = idx & 7;
        int r = row / UROWS, c = row - r * UROWS;
        int hh = hs + r, ww = ws + c;
        if (hh >= 0 && hh < HH && ww >= 0 && ww < WW) {
            float4 v = *(const float4*)(qkv + ((size_t)(hh * WW + ww)) * QKV_N
                                        + 2 * CC + head * HDIM + seg * 4);
            *(float4*)&kv_lds[row * HDIM + ((seg ^ (row & 7)) << 2)] = v;
        }
    }

    // softmax weights (in registers) while V is being staged
    float lsum = 0.f;
#pragma unroll
    for (int j = 0; j < 49; ++j) {
        float e = __expf(logits[j] - mx);
        logits[j] = e;
        lsum += e;
    }
    float out[HDIM];
#pragma unroll
    for (int d = 0; d < HDIM; ++d) out[d] = 0.f;
    __syncthreads();

    // ---- pass 2: PV ----
#pragma unroll
    for (int p = 0; p < 7; ++p) {
#pragma unroll
        for (int qq = 0; qq < 7; ++qq) {
            const int row = rbase + p * UROWS + qq;
            const float* vr = &kv_lds[row * HDIM];
            const int sw = (row & 7) << 2;
            const float pe = logits[p * 7 + qq];
#pragma unroll
            for (int d4 = 0; d4 < 8; ++d4) {
                float4 v4 = *(const float4*)(vr + ((d4 << 2) ^ sw));
                out[4*d4+0] = fmaf(pe, v4.x, out[4*d4+0]);
                out[4*d4+1] = fmaf(pe, v4.y, out[4*d4+1]);
                out[4*d4+2] = fmaf(pe, v4.z, out[4*d4+2]);
                out[4*d4+3] = fmaf(pe, v4.w, out[4*d4+3]);
            }
        }
    }

    const float inv = 1.0f / lsum;
    float* op = attn_out + ((size_t)(gy * WW + gx)) * CC + head * HDIM;
#pragma unroll
    for (int s = 0; s < 8; ++s) {
        float4 o;
        o.x = out[4*s+0] * inv; o.y = out[4*s+1] * inv;
        o.z = out[4*s+2] * inv; o.w = out[4*s+3] * inv;
        *(float4*)(op + s * 4) = o;
    }
}

// ---------------------------------------------------------------------------
extern "C" void kernel_launch(void* const* d_in, const int* in_sizes, int n_in,
                              void* d_out, int out_size, void* d_ws, size_t ws_size,
                              hipStream_t stream)
{
    const float* x      = (const float*)d_in[0];
    const float* w_qkv  = (const float*)d_in[1];
    const float* b_qkv  = (const float*)d_in[2];
    const float* w_proj = (const float*)d_in[3];
    const float* b_proj = (const float*)d_in[4];
    float* out = (float*)d_out;

    float* qkv  = (float*)d_ws;                       // 8192 x 768 fp32 = 24 MB
    float* attn = qkv + (size_t)NPIX * QKV_N;         // 8192 x 256 fp32 =  8 MB

    dim3 blk(256);
    // QKV projection: M=8192, N=768, K=256
    gemm_bias<<<dim3(NPIX / 128, QKV_N / 64), blk, 0, stream>>>(
        x, w_qkv, b_qkv, qkv, NPIX, QKV_N, CC);
    // neighborhood attention: grid (W/16, H/16, heads)
    na_attn<<<dim3(WW / 16, HH / 16, NHEAD), blk, 0, stream>>>(qkv, attn);
    // output projection: M=8192, N=256, K=256
    gemm_bias<<<dim3(NPIX / 128, CC / 64), blk, 0, stream>>>(
        attn, w_proj, b_proj, out, NPIX, CC, CC);
}

// Round 2
// 117.952 us; speedup vs baseline: 3.2272x; 3.2272x over previous
//
#include <hip/hip_runtime.h>
#include <cmath>

// Problem constants: B=1, H=64, W=128, C=256, 8 heads x 32 dim, 7x7 window.
#define HH 64
#define WW 128
#define CC 256
#define NHEAD 8
#define HDIM 32
#define NPIX (HH*WW)       // 8192
#define QKV_N (3*CC)       // 768

// ---------------------------------------------------------------------------
// Tiled fp32 GEMM with bias: C[M][N] = A[M][K] * B[K][N] + bias[N]
// BM=128, BN=64, BK=16, 256 threads, 8x4 micro-tile per thread.
// ---------------------------------------------------------------------------
__global__ __launch_bounds__(256)
void gemm_bias(const float* __restrict__ A, const float* __restrict__ B,
               const float* __restrict__ bias, float* __restrict__ C,
               int M, int N, int K)
{
    constexpr int BM = 128, BN = 64, BK = 16, TM = 8, TN = 4;
    __shared__ float As[BK][BM + 4];
    __shared__ float Bs[BK][BN + 4];

    const int tid = threadIdx.x;
    const int tx  = tid & 15;
    const int ty  = tid >> 4;
    const int bm  = blockIdx.x * BM;
    const int bn  = blockIdx.y * BN;

    const int ar  = tid >> 1;
    const int ak  = (tid & 1) * 8;
    const int bkr = tid >> 4;
    const int bnc = (tid & 15) * 4;

    float acc[TM][TN];
#pragma unroll
    for (int i = 0; i < TM; ++i)
#pragma unroll
        for (int j = 0; j < TN; ++j) acc[i][j] = 0.f;

    for (int k0 = 0; k0 < K; k0 += BK) {
        float4 a0 = *(const float4*)(A + (size_t)(bm + ar) * K + k0 + ak);
        float4 a1 = *(const float4*)(A + (size_t)(bm + ar) * K + k0 + ak + 4);
        float4 b0 = *(const float4*)(B + (size_t)(k0 + bkr) * N + bn + bnc);

        __syncthreads();
        As[ak + 0][ar] = a0.x; As[ak + 1][ar] = a0.y;
        As[ak + 2][ar] = a0.z; As[ak + 3][ar] = a0.w;
        As[ak + 4][ar] = a1.x; As[ak + 5][ar] = a1.y;
        As[ak + 6][ar] = a1.z; As[ak + 7][ar] = a1.w;
        *(float4*)&Bs[bkr][bnc] = b0;
        __syncthreads();

#pragma unroll
        for (int kk = 0; kk < BK; ++kk) {
            float4 av0 = *(const float4*)&As[kk][ty * TM];
            float4 av1 = *(const float4*)&As[kk][ty * TM + 4];
            float4 bv  = *(const float4*)&Bs[kk][tx * TN];
            float am[TM] = {av0.x, av0.y, av0.z, av0.w, av1.x, av1.y, av1.z, av1.w};
            float bb[TN] = {bv.x, bv.y, bv.z, bv.w};
#pragma unroll
            for (int i = 0; i < TM; ++i)
#pragma unroll
                for (int j = 0; j < TN; ++j)
                    acc[i][j] = fmaf(am[i], bb[j], acc[i][j]);
        }
    }

    float4 bvec = *(const float4*)(bias + bn + tx * TN);
#pragma unroll
    for (int i = 0; i < TM; ++i) {
        float4 o;
        o.x = acc[i][0] + bvec.x;
        o.y = acc[i][1] + bvec.y;
        o.z = acc[i][2] + bvec.z;
        o.w = acc[i][3] + bvec.w;
        *(float4*)(C + (size_t)(bm + ty * TM + i) * N + bn + tx * TN) = o;
    }
}

// ---------------------------------------------------------------------------
// Neighborhood attention, online-softmax (no max subtraction -- logits here
// have |s| < ~1 by construction, exp() is well-conditioned), K+V staged
// together. 8x16 pixel tile per block, 128 threads (1 px each), head =
// blockIdx.z. LDS = 14*22 rows x (32 K + 32 V) floats = 78848 B -> 2
// blocks/CU. XOR swizzle on the 16B granule within each 128B half-row
// (row stride is a multiple of 128B -> unswizzled piles onto banks 0-3).
// Per-thread live state ~70 floats: no spill (round-1 failure was out[]
// +logits[] in scratch: 356MB of scratch writes per dispatch).
// ---------------------------------------------------------------------------
#define UR 14
#define UC 22
#define NROW (UR*UC)   // 308

__global__ __launch_bounds__(128)
void na_attn(const float* __restrict__ qkv, float* __restrict__ attn_out)
{
    __shared__ float kv[NROW * 64];   // 78848 B

    const int head = blockIdx.z;
    const int h0 = blockIdx.y * 8;
    const int w0 = blockIdx.x * 16;
    const int hs = h0 - 3, ws = w0 - 3;
    const int tid = threadIdx.x;

    // ---- load own q (independent of staging) ----
    const int py = tid >> 4, px = tid & 15;
    const int gy = h0 + py, gx = w0 + px;
    const float scale = 0.17677669529663687f;   // 32^-0.5
    float q[HDIM];
    {
        const float* qp = qkv + (size_t)(gy * WW + gx) * QKV_N + head * HDIM;
#pragma unroll
        for (int s = 0; s < 8; ++s) {
            float4 v = *(const float4*)(qp + s * 4);
            q[4*s+0] = v.x * scale; q[4*s+1] = v.y * scale;
            q[4*s+2] = v.z * scale; q[4*s+3] = v.w * scale;
        }
    }

    // ---- stage K and V for the union window ----
    for (int idx = tid; idx < NROW * 16; idx += 128) {
        int u   = idx >> 4;
        int sel = (idx >> 3) & 1;     // 0 = K, 1 = V
        int seg = idx & 7;
        int r = u / UC, c = u - r * UC;
        int hh = hs + r, ww = ws + c;
        if (hh >= 0 && hh < HH && ww >= 0 && ww < WW) {
            float4 val = *(const float4*)(qkv + (size_t)(hh * WW + ww) * QKV_N
                                          + CC + sel * CC + head * HDIM + seg * 4);
            *(float4*)&kv[u * 64 + sel * 32 + ((seg ^ (u & 7)) << 2)] = val;
        }
    }
    __syncthreads();

    // window start in union coords
    const int ihs = min(max(gy - 3, 0), HH - 7);
    const int iws = min(max(gx - 3, 0), WW - 7);
    const int ubase = (ihs - hs) * UC + (iws - ws);

    float l = 0.f;
    float out[HDIM];
#pragma unroll
    for (int d = 0; d < HDIM; ++d) out[d] = 0.f;

#pragma unroll 1
    for (int p = 0; p < 7; ++p) {
#pragma unroll
        for (int qq = 0; qq < 7; ++qq) {
            const int u = ubase + p * UC + qq;
            const float* rowp = &kv[u * 64];
            const int su = u & 7;
            float s = 0.f;
#pragma unroll
            for (int d4 = 0; d4 < 8; ++d4) {
                float4 k4 = *(const float4*)(rowp + ((d4 ^ su) << 2));
                s = fmaf(q[4*d4+0], k4.x, s);
                s = fmaf(q[4*d4+1], k4.y, s);
                s = fmaf(q[4*d4+2], k4.z, s);
                s = fmaf(q[4*d4+3], k4.w, s);
            }
            const float e = __expf(s);
            l += e;
#pragma unroll
            for (int d4 = 0; d4 < 8; ++d4) {
                float4 v4 = *(const float4*)(rowp + 32 + ((d4 ^ su) << 2));
                out[4*d4+0] = fmaf(e, v4.x, out[4*d4+0]);
                out[4*d4+1] = fmaf(e, v4.y, out[4*d4+1]);
                out[4*d4+2] = fmaf(e, v4.z, out[4*d4+2]);
                out[4*d4+3] = fmaf(e, v4.w, out[4*d4+3]);
            }
        }
    }

    const float inv = 1.0f / l;
    float* op = attn_out + (size_t)(gy * WW + gx) * CC + head * HDIM;
#pragma unroll
    for (int s = 0; s < 8; ++s) {
        float4 o;
        o.x = out[4*s+0] * inv; o.y = out[4*s+1] * inv;
        o.z = out[4*s+2] * inv; o.w = out[4*s+3] * inv;
        *(float4*)(op + s * 4) = o;
    }
}

// ---------------------------------------------------------------------------
extern "C" void kernel_launch(void* const* d_in, const int* in_sizes, int n_in,
                              void* d_out, int out_size, void* d_ws, size_t ws_size,
                              hipStream_t stream)
{
    const float* x      = (const float*)d_in[0];
    const float* w_qkv  = (const float*)d_in[1];
    const float* b_qkv  = (const float*)d_in[2];
    const float* w_proj = (const float*)d_in[3];
    const float* b_proj = (const float*)d_in[4];
    float* out = (float*)d_out;

    float* qkv  = (float*)d_ws;                       // 8192 x 768 fp32 = 24 MB
    float* attn = qkv + (size_t)NPIX * QKV_N;         // 8192 x 256 fp32 =  8 MB

    // QKV projection: M=8192, N=768, K=256
    gemm_bias<<<dim3(NPIX / 128, QKV_N / 64), dim3(256), 0, stream>>>(
        x, w_qkv, b_qkv, qkv, NPIX, QKV_N, CC);
    // neighborhood attention: grid (W/16, H/8, heads), 128 threads
    na_attn<<<dim3(WW / 16, HH / 8, NHEAD), dim3(128), 0, stream>>>(qkv, attn);
    // output projection: M=8192, N=256, K=256
    gemm_bias<<<dim3(NPIX / 128, CC / 64), dim3(256), 0, stream>>>(
        attn, w_proj, b_proj, out, NPIX, CC, CC);
}

// Round 3
// 57.017 us; speedup vs baseline: 6.6762x; 2.0687x over previous
//
#include <hip/hip_runtime.h>
#include <cmath>

// B=1, H=64, W=128, C=256, 8 heads x 32 dim, 7x7 window.
#define HH 64
#define WW 128
#define CC 256
#define NHEAD 8
#define HDIM 32
#define NPIX (HH*WW)       // 8192
#define QKV_N (3*CC)       // 768

typedef __attribute__((ext_vector_type(8))) short short8v;  // 8 bf16 (4 VGPR)
typedef __attribute__((ext_vector_type(4))) float f32x4;    // MFMA C/D frag

__device__ __forceinline__ short f2bf(float f) {
    unsigned int u = __builtin_bit_cast(unsigned int, f);
    u += 0x7fffu + ((u >> 16) & 1u);        // RNE; inputs are normal floats
    return (short)(u >> 16);
}

// ---------------------------------------------------------------------------
// Weight prep: src [K][N] fp32 -> dst [N][K] bf16 (transposed so GEMM B-frags
// are contiguous short8 along k).
// ---------------------------------------------------------------------------
__global__ __launch_bounds__(256)
void transpose_cvt(const float* __restrict__ src, short* __restrict__ dst,
                   int K, int N)
{
    __shared__ float tile[32][33];
    const int bn = blockIdx.x * 32;
    const int bk = blockIdx.y * 32;
    const int tx = threadIdx.x & 31, ty = threadIdx.x >> 5;
#pragma unroll
    for (int i = 0; i < 32; i += 8)
        tile[ty + i][tx] = src[(size_t)(bk + ty + i) * N + bn + tx];
    __syncthreads();
#pragma unroll
    for (int i = 0; i < 32; i += 8)
        dst[(size_t)(bn + ty + i) * K + bk + tx] = f2bf(tile[tx][ty + i]);
}

// ---------------------------------------------------------------------------
// bf16 MFMA GEMM: C[M][N] = A[M][K] * Bt[N][K]^T + bias.  fp32 accumulate.
// A is fp32 (converted at stage time) when AF32, else bf16.
// 256 threads = 4 waves in 2x2; each wave (BM/2)x(BN/2) via 16x16x32 frags.
// LDS rows padded to 80B -> <=2-way bank conflicts on b128 frag reads.
// ---------------------------------------------------------------------------
template<int BM, int BN, bool AF32>
__global__ __launch_bounds__(256)
void gemm_mfma(const void* __restrict__ Av, const short* __restrict__ Bt,
               const float* __restrict__ bias, float* __restrict__ C,
               int M, int N, int K)
{
    constexpr int BK  = 32;
    constexpr int LDA = 40;              // shorts per LDS row (80 B)
    constexpr int NSA = BM / 64;         // 8-elem segments per thread (A)
    constexpr int NSB = BN / 64;
    __shared__ short As[BM * LDA];
    __shared__ short Bs[BN * LDA];

    const int tid  = threadIdx.x;
    const int lane = tid & 63;
    const int wave = tid >> 6;
    constexpr int WM = BM / 2, WN = BN / 2;
    constexpr int FM = WM / 16, FN = WN / 16;
    const int wm0 = (wave >> 1) * WM;
    const int wn0 = (wave & 1) * WN;
    const int bm = blockIdx.x * BM, bn = blockIdx.y * BN;
    const int l15 = lane & 15, l4 = lane >> 4;

    f32x4 acc[FM][FN];
#pragma unroll
    for (int i = 0; i < FM; ++i)
#pragma unroll
        for (int j = 0; j < FN; ++j) acc[i][j] = (f32x4){0.f, 0.f, 0.f, 0.f};

    const float* Af = (const float*)Av;
    const short* Ab = (const short*)Av;

    float4   afr[NSA][2];
    short8v  abr[NSA];
    short8v  bbr[NSB];

    int arow[NSA], aoff[NSA];
#pragma unroll
    for (int i = 0; i < NSA; ++i) {
        int s = tid + 256 * i;
        arow[i] = s >> 2; aoff[i] = (s & 3) * 8;
    }
    int brow[NSB], boff[NSB];
#pragma unroll
    for (int i = 0; i < NSB; ++i) {
        int s = tid + 256 * i;
        brow[i] = s >> 2; boff[i] = (s & 3) * 8;
    }

    auto loadA = [&](int t) {
        const int k0 = t * BK;
#pragma unroll
        for (int i = 0; i < NSA; ++i) {
            if (AF32) {
                const float* p = Af + (size_t)(bm + arow[i]) * K + k0 + aoff[i];
                afr[i][0] = *(const float4*)p;
                afr[i][1] = *(const float4*)(p + 4);
            } else {
                abr[i] = *(const short8v*)(Ab + (size_t)(bm + arow[i]) * K + k0 + aoff[i]);
            }
        }
    };
    auto loadB = [&](int t) {
        const int k0 = t * BK;
#pragma unroll
        for (int i = 0; i < NSB; ++i)
            bbr[i] = *(const short8v*)(Bt + (size_t)(bn + brow[i]) * K + k0 + boff[i]);
    };

    loadA(0); loadB(0);
    const int NT = K / BK;

    for (int t = 0; t < NT; ++t) {
        __syncthreads();                 // prior frag reads done
#pragma unroll
        for (int i = 0; i < NSA; ++i) {
            short8v w;
            if (AF32) {
                float4 x0 = afr[i][0], x1 = afr[i][1];
                w[0] = f2bf(x0.x); w[1] = f2bf(x0.y); w[2] = f2bf(x0.z); w[3] = f2bf(x0.w);
                w[4] = f2bf(x1.x); w[5] = f2bf(x1.y); w[6] = f2bf(x1.z); w[7] = f2bf(x1.w);
            } else {
                w = abr[i];
            }
            *(short8v*)&As[arow[i] * LDA + aoff[i]] = w;
        }
#pragma unroll
        for (int i = 0; i < NSB; ++i)
            *(short8v*)&Bs[brow[i] * LDA + boff[i]] = bbr[i];
        __syncthreads();
        if (t + 1 < NT) { loadA(t + 1); loadB(t + 1); }   // overlap MFMA below

        short8v af[FM], bfv[FN];
#pragma unroll
        for (int fm = 0; fm < FM; ++fm)
            af[fm] = *(const short8v*)&As[(wm0 + fm * 16 + l15) * LDA + l4 * 8];
#pragma unroll
        for (int fn = 0; fn < FN; ++fn)
            bfv[fn] = *(const short8v*)&Bs[(wn0 + fn * 16 + l15) * LDA + l4 * 8];
#pragma unroll
        for (int fm = 0; fm < FM; ++fm)
#pragma unroll
            for (int fn = 0; fn < FN; ++fn)
                acc[fm][fn] = __builtin_amdgcn_mfma_f32_16x16x32_bf16(
                    af[fm], bfv[fn], acc[fm][fn], 0, 0, 0);
    }

    const int col0 = bn + wn0 + l15;
    const int row0 = bm + wm0 + l4 * 4;
#pragma unroll
    for (int fn = 0; fn < FN; ++fn) {
        const float bv = bias[col0 + fn * 16];
#pragma unroll
        for (int fm = 0; fm < FM; ++fm)
#pragma unroll
            for (int r = 0; r < 4; ++r)
                C[(size_t)(row0 + fm * 16 + r) * N + col0 + fn * 16] =
                    acc[fm][fn][r] + bv;
    }
}

// ---------------------------------------------------------------------------
// Neighborhood attention: 8x16 pixel tile, 256 threads = 2 threads/pixel
// (head-dim split 16+16, __shfl_xor(1) combines the QK dot). K+V fp32 in
// LDS, XOR-swizzled 16B granules (row stride 256B -> unswizzled = bank
// pile-up). Online softmax without max-subtraction (|logit| < ~1 here).
// Emits bf16 directly (proj GEMM's A operand).
// ---------------------------------------------------------------------------
#define UR 14
#define UC 22
#define NROW (UR*UC)   // 308

__global__ __launch_bounds__(256)
void na_attn(const float* __restrict__ qkv, short* __restrict__ attn_bf)
{
    __shared__ float kv[NROW * 64];   // 78848 B -> 2 blocks/CU

    const int head = blockIdx.z;
    const int h0 = blockIdx.y * 8;
    const int w0 = blockIdx.x * 16;
    const int hs = h0 - 3, ws = w0 - 3;
    const int tid = threadIdx.x;
    const int px = tid >> 1, half = tid & 1;
    const int py = px >> 4, pxx = px & 15;
    const int gy = h0 + py, gx = w0 + pxx;
    const float scale = 0.17677669529663687f;   // 32^-0.5

    float q[16];
    {
        const float* qp = qkv + (size_t)(gy * WW + gx) * QKV_N + head * HDIM + half * 16;
#pragma unroll
        for (int s = 0; s < 4; ++s) {
            float4 v = *(const float4*)(qp + s * 4);
            q[4*s+0] = v.x * scale; q[4*s+1] = v.y * scale;
            q[4*s+2] = v.z * scale; q[4*s+3] = v.w * scale;
        }
    }

    // stage K and V for the union window
    for (int idx = tid; idx < NROW * 16; idx += 256) {
        int u   = idx >> 4;
        int sel = (idx >> 3) & 1;     // 0 = K, 1 = V
        int seg = idx & 7;
        int r = u / UC, c = u - r * UC;
        int hh = hs + r, ww = ws + c;
        if (hh >= 0 && hh < HH && ww >= 0 && ww < WW) {
            float4 val = *(const float4*)(qkv + (size_t)(hh * WW + ww) * QKV_N
                                          + CC + sel * CC + head * HDIM + seg * 4);
            *(float4*)&kv[u * 64 + sel * 32 + ((seg ^ (u & 7)) << 2)] = val;
        }
    }
    __syncthreads();

    const int ihs = min(max(gy - 3, 0), HH - 7);
    const int iws = min(max(gx - 3, 0), WW - 7);
    const int ubase = (ihs - hs) * UC + (iws - ws);

    float l = 0.f;
    float out[16];
#pragma unroll
    for (int d = 0; d < 16; ++d) out[d] = 0.f;

#pragma unroll 1
    for (int p = 0; p < 7; ++p) {
#pragma unroll
        for (int qq = 0; qq < 7; ++qq) {
            const int u = ubase + p * UC + qq;
            const float* rowp = &kv[u * 64];
            const int su = u & 7;
            float s = 0.f;
#pragma unroll
            for (int d4 = 0; d4 < 4; ++d4) {
                float4 k4 = *(const float4*)(rowp + (((4 * half + d4) ^ su) << 2));
                s = fmaf(q[4*d4+0], k4.x, s);
                s = fmaf(q[4*d4+1], k4.y, s);
                s = fmaf(q[4*d4+2], k4.z, s);
                s = fmaf(q[4*d4+3], k4.w, s);
            }
            s += __shfl_xor(s, 1);            // combine the two halves
            const float e = __expf(s);
            l += e;
#pragma unroll
            for (int d4 = 0; d4 < 4; ++d4) {
                float4 v4 = *(const float4*)(rowp + 32 + (((4 * half + d4) ^ su) << 2));
                out[4*d4+0] = fmaf(e, v4.x, out[4*d4+0]);
                out[4*d4+1] = fmaf(e, v4.y, out[4*d4+1]);
                out[4*d4+2] = fmaf(e, v4.z, out[4*d4+2]);
                out[4*d4+3] = fmaf(e, v4.w, out[4*d4+3]);
            }
        }
    }

    const float inv = 1.0f / l;
    short* op = attn_bf + (size_t)(gy * WW + gx) * CC + head * HDIM + half * 16;
    short8v o0, o1;
#pragma unroll
    for (int j = 0; j < 8; ++j) {
        o0[j] = f2bf(out[j] * inv);
        o1[j] = f2bf(out[8 + j] * inv);
    }
    *(short8v*)op = o0;
    *(short8v*)(op + 8) = o1;
}

// ---------------------------------------------------------------------------
extern "C" void kernel_launch(void* const* d_in, const int* in_sizes, int n_in,
                              void* d_out, int out_size, void* d_ws, size_t ws_size,
                              hipStream_t stream)
{
    const float* x      = (const float*)d_in[0];
    const float* w_qkv  = (const float*)d_in[1];
    const float* b_qkv  = (const float*)d_in[2];
    const float* w_proj = (const float*)d_in[3];
    const float* b_proj = (const float*)d_in[4];
    float* out = (float*)d_out;

    char* ws = (char*)d_ws;
    float* qkv      = (float*)ws;                              // 24 MB fp32
    short* attn_bf  = (short*)(ws + 25165824);                 //  4 MB bf16
    short* wqkv_t   = (short*)(ws + 29360128);                 // 768x256 bf16
    short* wproj_t  = (short*)(ws + 29753344);                 // 256x256 bf16

    // weight prep (transpose + bf16)
    transpose_cvt<<<dim3(QKV_N / 32, CC / 32), dim3(256), 0, stream>>>(
        w_qkv, wqkv_t, CC, QKV_N);
    transpose_cvt<<<dim3(CC / 32, CC / 32), dim3(256), 0, stream>>>(
        w_proj, wproj_t, CC, CC);

    // QKV projection: M=8192, N=768, K=256 (A = x fp32, converted at stage)
    gemm_mfma<128, 64, true><<<dim3(NPIX / 128, QKV_N / 64), dim3(256), 0, stream>>>(
        x, wqkv_t, b_qkv, qkv, NPIX, QKV_N, CC);

    // neighborhood attention -> bf16
    na_attn<<<dim3(WW / 16, HH / 8, NHEAD), dim3(256), 0, stream>>>(qkv, attn_bf);

    // output projection: M=8192, N=256, K=256 (A = attn bf16)
    gemm_mfma<64, 64, false><<<dim3(NPIX / 64, CC / 64), dim3(256), 0, stream>>>(
        attn_bf, wproj_t, b_proj, out, NPIX, CC, CC);
}

// Round 5
// 46.930 us; speedup vs baseline: 8.1113x; 1.2150x over previous
//
#include <hip/hip_runtime.h>
#include <cmath>

// B=1, H=64, W=128, C=256, 8 heads x 32 dim, 7x7 window.
#define HH 64
#define WW 128
#define CC 256
#define NHEAD 8
#define HDIM 32
#define NPIX (HH*WW)       // 8192
#define QKV_N (3*CC)       // 768

typedef __attribute__((ext_vector_type(8))) short short8v;  // 8 bf16
typedef __attribute__((ext_vector_type(4))) short short4v;  // 4 bf16
typedef __attribute__((ext_vector_type(4))) float f32x4;

__device__ __forceinline__ short f2bf(float f) {
    unsigned int u = __builtin_bit_cast(unsigned int, f);
    u += 0x7fffu + ((u >> 16) & 1u);
    return (short)(u >> 16);
}

// ---------------------------------------------------------------------------
// Weight prep: src [K][N] fp32 -> dst [N][K] bf16.
// ---------------------------------------------------------------------------
__global__ __launch_bounds__(256)
void transpose_cvt(const float* __restrict__ src, short* __restrict__ dst,
                   int K, int N)
{
    __shared__ float tile[32][33];
    const int bn = blockIdx.x * 32;
    const int bk = blockIdx.y * 32;
    const int tx = threadIdx.x & 31, ty = threadIdx.x >> 5;
#pragma unroll
    for (int i = 0; i < 32; i += 8)
        tile[ty + i][tx] = src[(size_t)(bk + ty + i) * N + bn + tx];
    __syncthreads();
#pragma unroll
    for (int i = 0; i < 32; i += 8)
        dst[(size_t)(bn + ty + i) * K + bk + tx] = f2bf(tile[tx][ty + i]);
}

// ---------------------------------------------------------------------------
// fp32 -> bf16 bulk convert (x). 8 elems/thread.
// ---------------------------------------------------------------------------
__global__ __launch_bounds__(256)
void cvt_bf(const float* __restrict__ src, short* __restrict__ dst)
{
    const int i = blockIdx.x * 256 + threadIdx.x;
    float4 a = ((const float4*)src)[i * 2];
    float4 b = ((const float4*)src)[i * 2 + 1];
    short8v o;
    o[0] = f2bf(a.x); o[1] = f2bf(a.y); o[2] = f2bf(a.z); o[3] = f2bf(a.w);
    o[4] = f2bf(b.x); o[5] = f2bf(b.y); o[6] = f2bf(b.z); o[7] = f2bf(b.w);
    ((short8v*)dst)[i] = o;
}

// ---------------------------------------------------------------------------
// bf16 MFMA GEMM: C = A[M][K] * Bt[N][K]^T + bias. A,Bt bf16; out bf16 or f32.
// 4 waves 2x2, 16x16x32 frags, BK=32. LDS rows padded to 80B (LDA=40): bank
// group = (20*row + 4*gran) % 32 -> uniform spread (64B rows were ~8-way).
// ---------------------------------------------------------------------------
template<int BM, int BN, bool OUT32>
__global__ __launch_bounds__(256)
void gemm_bf(const short* __restrict__ A, const short* __restrict__ Bt,
             const float* __restrict__ bias, void* __restrict__ Cv,
             int M, int N, int K)
{
    constexpr int BK = 32;
    constexpr int LDA = 40;            // padded row, shorts
    constexpr int NSA = BM / 64;
    constexpr int NSB = BN / 64;
    __shared__ short As[BM * LDA];
    __shared__ short Bs[BN * LDA];

    const int tid  = threadIdx.x;
    const int lane = tid & 63;
    const int wave = tid >> 6;
    constexpr int WM = BM / 2, WN = BN / 2;
    constexpr int FM = WM / 16, FN = WN / 16;
    const int wm0 = (wave >> 1) * WM;
    const int wn0 = (wave & 1) * WN;
    const int bm = blockIdx.x * BM, bn = blockIdx.y * BN;
    const int l15 = lane & 15, l4 = lane >> 4;

    f32x4 acc[FM][FN];
#pragma unroll
    for (int i = 0; i < FM; ++i)
#pragma unroll
        for (int j = 0; j < FN; ++j) acc[i][j] = (f32x4){0.f, 0.f, 0.f, 0.f};

    short8v ar[NSA], br[NSB];
    int arow[NSA], aoff[NSA], brow[NSB], boff[NSB];
#pragma unroll
    for (int i = 0; i < NSA; ++i) {
        int s = tid + 256 * i;
        arow[i] = s >> 2; aoff[i] = (s & 3) * 8;
    }
#pragma unroll
    for (int i = 0; i < NSB; ++i) {
        int s = tid + 256 * i;
        brow[i] = s >> 2; boff[i] = (s & 3) * 8;
    }

    auto loadA = [&](int t) {
#pragma unroll
        for (int i = 0; i < NSA; ++i)
            ar[i] = *(const short8v*)(A + (size_t)(bm + arow[i]) * K + t * BK + aoff[i]);
    };
    auto loadB = [&](int t) {
#pragma unroll
        for (int i = 0; i < NSB; ++i)
            br[i] = *(const short8v*)(Bt + (size_t)(bn + brow[i]) * K + t * BK + boff[i]);
    };

    loadA(0); loadB(0);
    const int NT = K / BK;

    for (int t = 0; t < NT; ++t) {
        __syncthreads();
#pragma unroll
        for (int i = 0; i < NSA; ++i)
            *(short8v*)&As[arow[i] * LDA + aoff[i]] = ar[i];
#pragma unroll
        for (int i = 0; i < NSB; ++i)
            *(short8v*)&Bs[brow[i] * LDA + boff[i]] = br[i];
        __syncthreads();
        if (t + 1 < NT) { loadA(t + 1); loadB(t + 1); }

        short8v af[FM], bf[FN];
#pragma unroll
        for (int fm = 0; fm < FM; ++fm)
            af[fm] = *(const short8v*)&As[(wm0 + fm * 16 + l15) * LDA + l4 * 8];
#pragma unroll
        for (int fn = 0; fn < FN; ++fn)
            bf[fn] = *(const short8v*)&Bs[(wn0 + fn * 16 + l15) * LDA + l4 * 8];
#pragma unroll
        for (int fm = 0; fm < FM; ++fm)
#pragma unroll
            for (int fn = 0; fn < FN; ++fn)
                acc[fm][fn] = __builtin_amdgcn_mfma_f32_16x16x32_bf16(
                    af[fm], bf[fn], acc[fm][fn], 0, 0, 0);
    }

    const int col0 = bn + wn0 + l15;
    const int row0 = bm + wm0 + l4 * 4;
#pragma unroll
    for (int fn = 0; fn < FN; ++fn) {
        const float bv = bias[col0 + fn * 16];
#pragma unroll
        for (int fm = 0; fm < FM; ++fm)
#pragma unroll
            for (int r = 0; r < 4; ++r) {
                const size_t off = (size_t)(row0 + fm * 16 + r) * N + col0 + fn * 16;
                if (OUT32) ((float*)Cv)[off] = acc[fm][fn][r] + bv;
                else       ((short*)Cv)[off] = f2bf(acc[fm][fn][r] + bv);
            }
    }
}

// ---------------------------------------------------------------------------
// Neighborhood attention via MFMA. Block = 4 y-strips x 16 px x 1 head;
// wave w owns strip y0+w. Key slot = i*24 + c (i: union row 0..9, c: union
// col 0..21, 22/23 pad). Wave window = 7 rows = 168 slots -> 11 S-frags
// (176-slot span; round-4 bug: 10 frags = 160 dropped keys).
//   S^T = mfma(K, Q)       A=K (m=key), B=Q (n=query)
//   P   = exp(S*scale)/l   pre-normalized, kept in registers (11 short4/lane)
//   O^T = mfma(V^T, P^T)   P^T B-frags built via __shfl from S-frag owners
// K rows padded to 80B (bank-uniform); V^T rows 528B (uniform); no P LDS.
// LDS = 36736B -> 4 blocks/CU. One barrier total.
// ---------------------------------------------------------------------------
#define KSLOT 248   // max S-read slot = 72 + 175 = 247
#define LDK   40    // K row pad (shorts)
#define VSLOT 264   // max PV-read slot = 72 + 191 = 263; all 264 staged

__global__ __launch_bounds__(256)
void na_mfma(const short* __restrict__ qkv, short* __restrict__ attn)
{
    __shared__ short Ksh[KSLOT * LDK];   // 19840 B
    __shared__ short Vsh[32 * VSLOT];    // 16896 B  [d][slot]

    const int x0 = blockIdx.x * 16;
    const int y0 = blockIdx.y * 4;
    const int head = blockIdx.z;
    const int tid = threadIdx.x, lane = tid & 63, w = tid >> 6;
    const int rs  = min(max(y0 - 3, 0), HH - 7);   // block union first row
    const int wsx = x0 - 3;                        // union first col (may be <0)

    // ---- stage K: 220 (row,col) x 4 d-granules ----
    for (int idx = tid; idx < 880; idx += 256) {
        int g = idx & 3, rc = idx >> 2;
        int i = rc / 22, c = rc - i * 22;
        int yy = rs + i, xx = wsx + c;
        if (yy < HH && (unsigned)xx < WW) {
            *(short8v*)&Ksh[(i * 24 + c) * LDK + g * 8] =
                *(const short8v*)(qkv + (size_t)(yy * WW + xx) * QKV_N
                                  + CC + head * HDIM + g * 8);
        }
    }
    // ---- stage V^T: 66 slot-quads x 4 d-granules; zero-fills ALL 264 slots ----
    for (int idx = tid; idx < 264; idx += 256) {
        int g = idx & 3, q2 = idx >> 2;
        int i = q2 / 6, cq = q2 - i * 6;
        int yy = rs + i;
        short8v vv[4];
#pragma unroll
        for (int j = 0; j < 4; ++j) {
            int c = cq * 4 + j, xx = wsx + c;
            if (yy < HH && c < 22 && (unsigned)xx < WW)
                vv[j] = *(const short8v*)(qkv + (size_t)(yy * WW + xx) * QKV_N
                                          + 2 * CC + head * HDIM + g * 8);
            else {
                short8v z = {0,0,0,0,0,0,0,0};
                vv[j] = z;
            }
        }
#pragma unroll
        for (int jd = 0; jd < 8; ++jd) {
            short4v s4 = {vv[0][jd], vv[1][jd], vv[2][jd], vv[3][jd]};
            *(short4v*)&Vsh[(g * 8 + jd) * VSLOT + i * 24 + cq * 4] = s4;
        }
    }

    // ---- own Q fragment (B operand: n=query=l15, k=d) ----
    const int l15 = lane & 15, l4 = lane >> 4;
    const int y = y0 + w;
    short8v qf = *(const short8v*)(qkv + (size_t)(y * WW + x0 + l15) * QKV_N
                                   + head * HDIM + l4 * 8);
    __syncthreads();

    const int wbase = (min(max(y - 3, 0), HH - 7) - rs) * 24;   // 0, 24, 48, 72

    // ---- S^T = mfma(K, Q): 11 frags over 176 slots ----
    f32x4 sacc[11];
#pragma unroll
    for (int kc = 0; kc < 11; ++kc) {
        short8v kf = *(const short8v*)&Ksh[(wbase + kc * 16 + l15) * LDK + l4 * 8];
        f32x4 z = {0.f, 0.f, 0.f, 0.f};
        sacc[kc] = __builtin_amdgcn_mfma_f32_16x16x32_bf16(kf, qf, z, 0, 0, 0);
    }

    // ---- mask + exp (in place) + row-sum ----
    const int xq = x0 + l15;
    const int cw = min(max(xq - 3, 0), WW - 7) - wsx;   // valid c in [cw, cw+6]
    const float scale = 0.17677669529663687f;           // 32^-0.5
    float lsum = 0.f;
#pragma unroll
    for (int kc = 0; kc < 11; ++kc) {
#pragma unroll
        for (int r = 0; r < 4; ++r) {
            int kl = kc * 16 + l4 * 4 + r;
            int row = kl / 24;
            int c = kl - row * 24;
            bool valid = (row < 7) && (c >= cw) && (c <= cw + 6);
            float e = valid ? __expf(sacc[kc][r] * scale) : 0.f;
            sacc[kc][r] = e;
            lsum += e;
        }
    }
    lsum += __shfl_xor(lsum, 16);
    lsum += __shfl_xor(lsum, 32);
    const float inv = 1.0f / lsum;

    // ---- pack P (pre-normalized) into 12 short4 frags (frag 11 = 0) ----
    short4v pf[12];
#pragma unroll
    for (int kc = 0; kc < 11; ++kc) {
        short4v pk;
#pragma unroll
        for (int r = 0; r < 4; ++r) pk[r] = f2bf(sacc[kc][r] * inv);
        pf[kc] = pk;
    }
    pf[11] = (short4v){0, 0, 0, 0};

    // ---- O^T = mfma(V^T, P^T): 6 key-chunks x 2 d-halves ----
    // B-frag (P^T) for chunk kc2: lane (l4,l15) needs keys kc2*32+8*l4+[0,8),
    // held by lanes 32*(l4&1)+l15 (+16) in frag 2*kc2 (l4<2) or 2*kc2+1.
    const int src0 = ((l4 & 1) << 5) + l15;
    const int src1 = src0 + 16;
    const bool hi = (l4 & 2) != 0;
    f32x4 oacc[2];
    oacc[0] = (f32x4){0.f, 0.f, 0.f, 0.f};
    oacc[1] = (f32x4){0.f, 0.f, 0.f, 0.f};
#pragma unroll
    for (int kc2 = 0; kc2 < 6; ++kc2) {
        int lo0 = __builtin_bit_cast(int, *(const int*)&pf[2 * kc2]);
        int lo1 = ((const int*)&pf[2 * kc2])[1];
        int hi0 = ((const int*)&pf[2 * kc2 + 1])[0];
        int hi1 = ((const int*)&pf[2 * kc2 + 1])[1];
        int a0 = __shfl(lo0, src0), a1 = __shfl(lo1, src0);
        int a2 = __shfl(lo0, src1), a3 = __shfl(lo1, src1);
        int b0 = __shfl(hi0, src0), b1 = __shfl(hi1, src0);
        int b2 = __shfl(hi0, src1), b3 = __shfl(hi1, src1);
        int w0 = hi ? b0 : a0, w1 = hi ? b1 : a1;
        int w2 = hi ? b2 : a2, w3 = hi ? b3 : a3;
        int wv[4] = {w0, w1, w2, w3};
        short8v bfrag = *(const short8v*)wv;
#pragma unroll
        for (int nc = 0; nc < 2; ++nc) {
            short8v vf = *(const short8v*)&Vsh[(nc * 16 + l15) * VSLOT
                                               + wbase + kc2 * 32 + l4 * 8];
            oacc[nc] = __builtin_amdgcn_mfma_f32_16x16x32_bf16(vf, bfrag, oacc[nc], 0, 0, 0);
        }
    }

    // ---- store: C-frag col=n=query=l15, row=m=d=(l4*4+r) within 16 ----
    short* op = attn + (size_t)(y * WW + x0 + l15) * CC + head * HDIM;
#pragma unroll
    for (int nc = 0; nc < 2; ++nc) {
        short4v o;
#pragma unroll
        for (int r = 0; r < 4; ++r) o[r] = f2bf(oacc[nc][r]);
        *(short4v*)(op + nc * 16 + l4 * 4) = o;
    }
}

// ---------------------------------------------------------------------------
extern "C" void kernel_launch(void* const* d_in, const int* in_sizes, int n_in,
                              void* d_out, int out_size, void* d_ws, size_t ws_size,
                              hipStream_t stream)
{
    const float* x      = (const float*)d_in[0];
    const float* w_qkv  = (const float*)d_in[1];
    const float* b_qkv  = (const float*)d_in[2];
    const float* w_proj = (const float*)d_in[3];
    const float* b_proj = (const float*)d_in[4];
    float* out = (float*)d_out;

    char* ws = (char*)d_ws;
    short* qkv_bf  = (short*)ws;                    // 8192x768 bf16 = 12 MB
    short* attn_bf = (short*)(ws + 12582912);       // 8192x256 bf16 =  4 MB
    short* x_bf    = (short*)(ws + 16777216);       // 8192x256 bf16 =  4 MB
    short* wqkv_t  = (short*)(ws + 20971520);       // 768x256 bf16
    short* wproj_t = (short*)(ws + 21364736);       // 256x256 bf16

    transpose_cvt<<<dim3(QKV_N / 32, CC / 32), dim3(256), 0, stream>>>(
        w_qkv, wqkv_t, CC, QKV_N);
    transpose_cvt<<<dim3(CC / 32, CC / 32), dim3(256), 0, stream>>>(
        w_proj, wproj_t, CC, CC);
    cvt_bf<<<dim3(NPIX * CC / (256 * 8)), dim3(256), 0, stream>>>(x, x_bf);

    // QKV: M=8192, N=768, K=256 -> bf16
    gemm_bf<128, 128, false><<<dim3(NPIX / 128, QKV_N / 128), dim3(256), 0, stream>>>(
        x_bf, wqkv_t, b_qkv, qkv_bf, NPIX, QKV_N, CC);

    // attention
    na_mfma<<<dim3(WW / 16, HH / 4, NHEAD), dim3(256), 0, stream>>>(qkv_bf, attn_bf);

    // proj: M=8192, N=256, K=256 -> fp32 out
    gemm_bf<64, 128, true><<<dim3(NPIX / 64, CC / 128), dim3(256), 0, stream>>>(
        attn_bf, wproj_t, b_proj, out, NPIX, CC, CC);
}

// Round 6
// 41.615 us; speedup vs baseline: 9.1471x; 1.1277x over previous
//
#include <hip/hip_runtime.h>
#include <cmath>

// B=1, H=64, W=128, C=256, 8 heads x 32 dim, 7x7 window.
#define HH 64
#define WW 128
#define CC 256
#define NHEAD 8
#define HDIM 32
#define NPIX (HH*WW)       // 8192
#define QKV_N (3*CC)       // 768

typedef __attribute__((ext_vector_type(8))) short short8v;  // 8 bf16
typedef __attribute__((ext_vector_type(4))) short short4v;  // 4 bf16
typedef __attribute__((ext_vector_type(4))) float f32x4;
typedef unsigned int u32;

__device__ __forceinline__ short f2bf(float f) {
    unsigned int u = __builtin_bit_cast(unsigned int, f);
    u += 0x7fffu + ((u >> 16) & 1u);
    return (short)(u >> 16);
}

// ---------------------------------------------------------------------------
// prep: one kernel for all input conversion.
//   blocks [0,1024):   x fp32 -> bf16 (8 elems/thread)
//   blocks [1024,1216): w_qkv [256][768] -> wqkv_t [768][256] bf16
//   blocks [1216,1280): w_proj [256][256] -> wproj_t [256][256] bf16
// ---------------------------------------------------------------------------
__global__ __launch_bounds__(256)
void prep(const float* __restrict__ x, const float* __restrict__ w_qkv,
          const float* __restrict__ w_proj, short* __restrict__ x_bf,
          short* __restrict__ wqkv_t, short* __restrict__ wproj_t)
{
    __shared__ float tile[32][33];
    const int b = blockIdx.x;
    if (b < 1024) {
        const int i = b * 256 + threadIdx.x;
        float4 a = ((const float4*)x)[i * 2];
        float4 c = ((const float4*)x)[i * 2 + 1];
        short8v o;
        o[0] = f2bf(a.x); o[1] = f2bf(a.y); o[2] = f2bf(a.z); o[3] = f2bf(a.w);
        o[4] = f2bf(c.x); o[5] = f2bf(c.y); o[6] = f2bf(c.z); o[7] = f2bf(c.w);
        ((short8v*)x_bf)[i] = o;
        return;
    }
    const float* src; short* dst; int N, idx;
    if (b < 1216) { idx = b - 1024; src = w_qkv;  dst = wqkv_t;  N = QKV_N; }
    else          { idx = b - 1216; src = w_proj; dst = wproj_t; N = CC;    }
    const int nbx = N / 32;
    const int bn = (idx % nbx) * 32;
    const int bk = (idx / nbx) * 32;
    const int tx = threadIdx.x & 31, ty = threadIdx.x >> 5;
#pragma unroll
    for (int i = 0; i < 32; i += 8)
        tile[ty + i][tx] = src[(size_t)(bk + ty + i) * N + bn + tx];
    __syncthreads();
#pragma unroll
    for (int i = 0; i < 32; i += 8)
        dst[(size_t)(bn + ty + i) * CC + bk + tx] = f2bf(tile[tx][ty + i]);
}

// ---------------------------------------------------------------------------
// bf16 MFMA GEMM: C = A[M][K] * Bt[N][K]^T + bias. A,Bt bf16; out bf16/f32.
// 4 waves 2x2, 16x16x32 frags, BK=32. Staging via global_load_lds (direct
// HBM->LDS, no register roundtrip): linear LDS layout [row][k] 64B rows,
// dest = base + tid*16B (the wave-uniform+lane*16 HW pattern). Double-
// buffered: loads for tile t+1 are in flight during tile t's MFMAs; the
// compiler's vmcnt drain at the barrier closes the pipeline.
// Frag reads at 64B rows spread uniformly over the 8 16B slot-groups
// (residue (4*l15+l4) mod 8) -> at the b128 floor, no extra conflict.
// ---------------------------------------------------------------------------
template<int BM, int BN, bool OUT32>
__global__ __launch_bounds__(256)
void gemm_bf(const short* __restrict__ A, const short* __restrict__ Bt,
             const float* __restrict__ bias, void* __restrict__ Cv,
             int M, int N, int K)
{
    constexpr int BK  = 32;
    constexpr int NGA = BM * BK / 2048;   // 16B granules per thread (A)
    constexpr int NGB = BN * BK / 2048;
    __shared__ short As[2][BM * BK];
    __shared__ short Bs[2][BN * BK];

    const int tid  = threadIdx.x;
    const int lane = tid & 63;
    const int wave = tid >> 6;
    constexpr int WM = BM / 2, WN = BN / 2;
    constexpr int FM = WM / 16, FN = WN / 16;
    const int wm0 = (wave >> 1) * WM;
    const int wn0 = (wave & 1) * WN;
    const int bm = blockIdx.x * BM, bn = blockIdx.y * BN;
    const int l15 = lane & 15, l4 = lane >> 4;

    f32x4 acc[FM][FN];
#pragma unroll
    for (int i = 0; i < FM; ++i)
#pragma unroll
        for (int j = 0; j < FN; ++j) acc[i][j] = (f32x4){0.f, 0.f, 0.f, 0.f};

    auto stage = [&](int buf, int t) {
#pragma unroll
        for (int i = 0; i < NGA; ++i) {
            const int g = tid + 256 * i;
            __builtin_amdgcn_global_load_lds(
                (const __attribute__((address_space(1))) u32*)
                    (A + (size_t)(bm + (g >> 2)) * K + t * BK + (g & 3) * 8),
                (__attribute__((address_space(3))) u32*)&As[buf][g * 8],
                16, 0, 0);
        }
#pragma unroll
        for (int i = 0; i < NGB; ++i) {
            const int g = tid + 256 * i;
            __builtin_amdgcn_global_load_lds(
                (const __attribute__((address_space(1))) u32*)
                    (Bt + (size_t)(bn + (g >> 2)) * K + t * BK + (g & 3) * 8),
                (__attribute__((address_space(3))) u32*)&Bs[buf][g * 8],
                16, 0, 0);
        }
    };

    stage(0, 0);
    const int NT = K / BK;

    for (int t = 0; t < NT; ++t) {
        const int cur = t & 1;
        __syncthreads();                     // stage(t) landed; buf reads done
        if (t + 1 < NT) stage(cur ^ 1, t + 1);

        short8v af[FM], bf[FN];
#pragma unroll
        for (int fm = 0; fm < FM; ++fm)
            af[fm] = *(const short8v*)&As[cur][(wm0 + fm * 16 + l15) * BK + l4 * 8];
#pragma unroll
        for (int fn = 0; fn < FN; ++fn)
            bf[fn] = *(const short8v*)&Bs[cur][(wn0 + fn * 16 + l15) * BK + l4 * 8];
#pragma unroll
        for (int fm = 0; fm < FM; ++fm)
#pragma unroll
            for (int fn = 0; fn < FN; ++fn)
                acc[fm][fn] = __builtin_amdgcn_mfma_f32_16x16x32_bf16(
                    af[fm], bf[fn], acc[fm][fn], 0, 0, 0);
    }

    const int col0 = bn + wn0 + l15;
    const int row0 = bm + wm0 + l4 * 4;
#pragma unroll
    for (int fn = 0; fn < FN; ++fn) {
        const float bv = bias[col0 + fn * 16];
#pragma unroll
        for (int fm = 0; fm < FM; ++fm)
#pragma unroll
            for (int r = 0; r < 4; ++r) {
                const size_t off = (size_t)(row0 + fm * 16 + r) * N + col0 + fn * 16;
                if (OUT32) ((float*)Cv)[off] = acc[fm][fn][r] + bv;
                else       ((short*)Cv)[off] = f2bf(acc[fm][fn][r] + bv);
            }
    }
}

// ---------------------------------------------------------------------------
// Neighborhood attention via MFMA (unchanged from round 5; proven correct).
// Block = 4 y-strips x 16 px x 1 head; wave w owns strip y0+w. Key slot =
// i*24 + c. Wave window = 7 rows = 168 slots -> 11 S-frags (176-slot span).
//   S^T = mfma(K, Q); P = exp(S*scale)/l in registers; O^T = mfma(V^T, P^T)
// with P^T B-frags built via __shfl. LDS 36.7KB -> 4 blocks/CU, one barrier.
// ---------------------------------------------------------------------------
#define KSLOT 248
#define LDK   40
#define VSLOT 264

__global__ __launch_bounds__(256)
void na_mfma(const short* __restrict__ qkv, short* __restrict__ attn)
{
    __shared__ short Ksh[KSLOT * LDK];   // 19840 B
    __shared__ short Vsh[32 * VSLOT];    // 16896 B  [d][slot]

    const int x0 = blockIdx.x * 16;
    const int y0 = blockIdx.y * 4;
    const int head = blockIdx.z;
    const int tid = threadIdx.x, lane = tid & 63, w = tid >> 6;
    const int rs  = min(max(y0 - 3, 0), HH - 7);
    const int wsx = x0 - 3;

    // ---- stage K ----
    for (int idx = tid; idx < 880; idx += 256) {
        int g = idx & 3, rc = idx >> 2;
        int i = rc / 22, c = rc - i * 22;
        int yy = rs + i, xx = wsx + c;
        if (yy < HH && (unsigned)xx < WW) {
            *(short8v*)&Ksh[(i * 24 + c) * LDK + g * 8] =
                *(const short8v*)(qkv + (size_t)(yy * WW + xx) * QKV_N
                                  + CC + head * HDIM + g * 8);
        }
    }
    // ---- stage V^T (zero-fills all 264 slots) ----
    for (int idx = tid; idx < 264; idx += 256) {
        int g = idx & 3, q2 = idx >> 2;
        int i = q2 / 6, cq = q2 - i * 6;
        int yy = rs + i;
        short8v vv[4];
#pragma unroll
        for (int j = 0; j < 4; ++j) {
            int c = cq * 4 + j, xx = wsx + c;
            if (yy < HH && c < 22 && (unsigned)xx < WW)
                vv[j] = *(const short8v*)(qkv + (size_t)(yy * WW + xx) * QKV_N
                                          + 2 * CC + head * HDIM + g * 8);
            else {
                short8v z = {0,0,0,0,0,0,0,0};
                vv[j] = z;
            }
        }
#pragma unroll
        for (int jd = 0; jd < 8; ++jd) {
            short4v s4 = {vv[0][jd], vv[1][jd], vv[2][jd], vv[3][jd]};
            *(short4v*)&Vsh[(g * 8 + jd) * VSLOT + i * 24 + cq * 4] = s4;
        }
    }

    const int l15 = lane & 15, l4 = lane >> 4;
    const int y = y0 + w;
    short8v qf = *(const short8v*)(qkv + (size_t)(y * WW + x0 + l15) * QKV_N
                                   + head * HDIM + l4 * 8);
    __syncthreads();

    const int wbase = (min(max(y - 3, 0), HH - 7) - rs) * 24;

    // ---- S^T = mfma(K, Q): 11 frags ----
    f32x4 sacc[11];
#pragma unroll
    for (int kc = 0; kc < 11; ++kc) {
        short8v kf = *(const short8v*)&Ksh[(wbase + kc * 16 + l15) * LDK + l4 * 8];
        f32x4 z = {0.f, 0.f, 0.f, 0.f};
        sacc[kc] = __builtin_amdgcn_mfma_f32_16x16x32_bf16(kf, qf, z, 0, 0, 0);
    }

    // ---- mask + exp + row-sum ----
    const int xq = x0 + l15;
    const int cw = min(max(xq - 3, 0), WW - 7) - wsx;
    const float scale = 0.17677669529663687f;
    float lsum = 0.f;
#pragma unroll
    for (int kc = 0; kc < 11; ++kc) {
#pragma unroll
        for (int r = 0; r < 4; ++r) {
            int kl = kc * 16 + l4 * 4 + r;
            int row = kl / 24;
            int c = kl - row * 24;
            bool valid = (row < 7) && (c >= cw) && (c <= cw + 6);
            float e = valid ? __expf(sacc[kc][r] * scale) : 0.f;
            sacc[kc][r] = e;
            lsum += e;
        }
    }
    lsum += __shfl_xor(lsum, 16);
    lsum += __shfl_xor(lsum, 32);
    const float inv = 1.0f / lsum;

    short4v pf[12];
#pragma unroll
    for (int kc = 0; kc < 11; ++kc) {
        short4v pk;
#pragma unroll
        for (int r = 0; r < 4; ++r) pk[r] = f2bf(sacc[kc][r] * inv);
        pf[kc] = pk;
    }
    pf[11] = (short4v){0, 0, 0, 0};

    // ---- O^T = mfma(V^T, P^T) ----
    const int src0 = ((l4 & 1) << 5) + l15;
    const int src1 = src0 + 16;
    const bool hi = (l4 & 2) != 0;
    f32x4 oacc[2];
    oacc[0] = (f32x4){0.f, 0.f, 0.f, 0.f};
    oacc[1] = (f32x4){0.f, 0.f, 0.f, 0.f};
#pragma unroll
    for (int kc2 = 0; kc2 < 6; ++kc2) {
        int lo0 = ((const int*)&pf[2 * kc2])[0];
        int lo1 = ((const int*)&pf[2 * kc2])[1];
        int hi0 = ((const int*)&pf[2 * kc2 + 1])[0];
        int hi1 = ((const int*)&pf[2 * kc2 + 1])[1];
        int a0 = __shfl(lo0, src0), a1 = __shfl(lo1, src0);
        int a2 = __shfl(lo0, src1), a3 = __shfl(lo1, src1);
        int b0 = __shfl(hi0, src0), b1 = __shfl(hi1, src0);
        int b2 = __shfl(hi0, src1), b3 = __shfl(hi1, src1);
        int w0 = hi ? b0 : a0, w1 = hi ? b1 : a1;
        int w2 = hi ? b2 : a2, w3 = hi ? b3 : a3;
        int wv[4] = {w0, w1, w2, w3};
        short8v bfrag = *(const short8v*)wv;
#pragma unroll
        for (int nc = 0; nc < 2; ++nc) {
            short8v vf = *(const short8v*)&Vsh[(nc * 16 + l15) * VSLOT
                                               + wbase + kc2 * 32 + l4 * 8];
            oacc[nc] = __builtin_amdgcn_mfma_f32_16x16x32_bf16(vf, bfrag, oacc[nc], 0, 0, 0);
        }
    }

    short* op = attn + (size_t)(y * WW + x0 + l15) * CC + head * HDIM;
#pragma unroll
    for (int nc = 0; nc < 2; ++nc) {
        short4v o;
#pragma unroll
        for (int r = 0; r < 4; ++r) o[r] = f2bf(oacc[nc][r]);
        *(short4v*)(op + nc * 16 + l4 * 4) = o;
    }
}

// ---------------------------------------------------------------------------
extern "C" void kernel_launch(void* const* d_in, const int* in_sizes, int n_in,
                              void* d_out, int out_size, void* d_ws, size_t ws_size,
                              hipStream_t stream)
{
    const float* x      = (const float*)d_in[0];
    const float* w_qkv  = (const float*)d_in[1];
    const float* b_qkv  = (const float*)d_in[2];
    const float* w_proj = (const float*)d_in[3];
    const float* b_proj = (const float*)d_in[4];
    float* out = (float*)d_out;

    char* ws = (char*)d_ws;
    short* qkv_bf  = (short*)ws;                    // 8192x768 bf16 = 12 MB
    short* attn_bf = (short*)(ws + 12582912);       // 8192x256 bf16 =  4 MB
    short* x_bf    = (short*)(ws + 16777216);       // 8192x256 bf16 =  4 MB
    short* wqkv_t  = (short*)(ws + 20971520);       // 768x256 bf16
    short* wproj_t = (short*)(ws + 21364736);       // 256x256 bf16

    // all input prep in one node
    prep<<<dim3(1280), dim3(256), 0, stream>>>(x, w_qkv, w_proj,
                                               x_bf, wqkv_t, wproj_t);

    // QKV: M=8192, N=768, K=256 -> bf16
    gemm_bf<128, 128, false><<<dim3(NPIX / 128, QKV_N / 128), dim3(256), 0, stream>>>(
        x_bf, wqkv_t, b_qkv, qkv_bf, NPIX, QKV_N, CC);

    // attention
    na_mfma<<<dim3(WW / 16, HH / 4, NHEAD), dim3(256), 0, stream>>>(qkv_bf, attn_bf);

    // proj: M=8192, N=256, K=256 -> fp32 out
    gemm_bf<64, 128, true><<<dim3(NPIX / 64, CC / 128), dim3(256), 0, stream>>>(
        attn_bf, wproj_t, b_proj, out, NPIX, CC, CC);
}